// Round 16
// baseline (114.926 us; speedup 1.0000x reference)
//
#include <hip/hip_runtime.h>

// AdaptiveAngleConv round 16: R14 schedule with nf=4 (wave tile M=64 x N=128).
//   - 6 ds_read_b128 per 8 MFMA (ratio 0.75): LDS critical path 46 -> 34.6 us
//   - 4 full-width tiles (it = 0..3), restage 2 rows per tile, 6 barriers total
//   - bias as 37th K-step (frees 32 bv VGPRs; acc is 128 AGPR now)
//   - loads at tile start -> pack between lgkm-only barrier pair (R14-proven)
//   - NT stores fire-and-forget; gll A-staging; NO setprio.
// LDS: A 75,776 (37 kc) + ring 4*16,640 = 142,336 B. 256 blocks x 512 thr.

#define CIN 64
#define COUT 64
#define HH 128
#define WW 128
#define NB 16
#define HW (HH*WW)

typedef short bf16x8 __attribute__((ext_vector_type(8)));
typedef float f32x16 __attribute__((ext_vector_type(16)));
#define AS1 __attribute__((address_space(1)))
#define AS3 __attribute__((address_space(3)))

// APERM_d[a][t] = PERMS[a][t] * 8192 : A slab byte offset paired with x-tap t
// (v13/R14-validated, absmax 0.5).
__device__ __constant__ unsigned APERM_d[4][9] = {
  {0,8192,16384,24576,32768,40960,49152,57344,65536},
  {24576,0,8192,49152,32768,16384,57344,65536,40960},
  {49152,24576,0,57344,32768,8192,65536,40960,16384},
  {57344,49152,24576,65536,32768,0,40960,16384,8192},
};

static __device__ __forceinline__ unsigned short f2bf(float f) {
  unsigned u = __builtin_bit_cast(unsigned, f);
  return (unsigned short)((u + 0x7FFFu + ((u >> 16) & 1u)) >> 16);
}
static __device__ __forceinline__ unsigned pk2(float lo, float hi) {
  return (unsigned)f2bf(lo) | ((unsigned)f2bf(hi) << 16);
}

// Canonical A + bias kstep (v9/v13/R15-validated): e = ((kc*2 + half)*64 + cm)*8 + j.
// kc<36: ci = (kc&3)*16 + half*8 + j, value W[cm][ci][kc>>2].
// kc==36: bias[cm] one-hot at (half==0, j==0). 37,888 bf16 = 75,776 B.
__global__ void build_A_kernel(const float* __restrict__ wgt,
                               const float* __restrict__ bias,
                               unsigned short* __restrict__ A) {
  const int e = blockIdx.x * 256 + threadIdx.x;
  const int j = e & 7;
  const int cm = (e >> 3) & 63;
  const int half = (e >> 9) & 1;
  const int kc = e >> 10;
  if (kc < 36) {
    const int s = kc >> 2, q = kc & 3;
    const int ci = q * 16 + half * 8 + j;
    A[e] = f2bf(wgt[(cm * CIN + ci) * 9 + s]);
  } else if (kc == 36) {
    A[e] = (half == 0 && j == 0) ? f2bf(bias[cm]) : (unsigned short)0;
  }
}

static __device__ __forceinline__ void lgkm_barrier() {
  asm volatile("s_waitcnt lgkmcnt(0)" ::: "memory");
  __builtin_amdgcn_s_barrier();
}

// ring: byte(rs, ci, wI) = XS_OFF + rs*XS_ROW + (ci>>3)*XS_SLOT + wI*16 + (ci&7)*2
//   x row hx -> slot (hx - hbase + 1) & 3 ; wI = 0..129 = x col -1..128
#define XS_SLOT 2080
#define XS_ROW  16640
#define XS_OFF  75776
#define LDS_BYTES (XS_OFF + 4 * XS_ROW)   // 142,336 B

__global__ __launch_bounds__(512) void aconv_v16_kernel(
    const float* __restrict__ x,              // [B][CIN][H][W] fp32
    const unsigned short* __restrict__ Ag,    // 37 kc canonical + bias
    float* __restrict__ out)                  // [4][B][COUT][H][W] fp32
{
  __shared__ __align__(16) unsigned char lds[LDS_BYTES];

  const int tid = threadIdx.x;
  const int lane = tid & 63;
  const int wid = tid >> 6;          // 8 waves = (angle 0..3) x (row 0..1)
  const int a   = wid >> 1;          // angle
  const int row = wid & 1;           // output row within 2-row tile
  const int half = lane >> 5;
  const int ln = lane & 31;

  const int b   = blockIdx.x >> 4;
  const int rem = blockIdx.x & 15;
  const int hbase = rem * 8;

  const unsigned char* Agb = (const unsigned char*)Ag;
  AS3 unsigned char* ldsa = (AS3 unsigned char*)lds;

  // ---- stage A via global_load_lds: 74 granules of 1024 B (zero staging VGPRs) ----
  #pragma unroll
  for (int j = 0; j < 10; ++j) {
    const int i = wid + j * 8;       // 0..73
    if (i < 74)
      __builtin_amdgcn_global_load_lds(
          (const AS1 unsigned*)(Agb + i * 1024 + lane * 16),
          (AS3 unsigned*)(ldsa + i * 1024), 16, 0, 0);
  }

  // ---- prologue: stage x rows hbase-1..hbase+2 (full width) into slots 0..3 ----
  // 4 rows x 8 slots x 130 cols = 4160 granules (16 B each)
  #pragma unroll
  for (int i = 0; i < 9; ++i) {
    const int g = tid + i * 512;
    if (g < 4160) {
      const int r    = g / 1040;
      const int rest = g - r * 1040;
      const int slot = rest / 130;
      const int wI   = rest - slot * 130;
      const int gh = hbase - 1 + r;
      const int gw = wI - 1;
      const bool inb = ((unsigned)gh < HH) && ((unsigned)gw < WW);
      const float* xp = x + (size_t)(b * CIN + slot * 8) * HW + (size_t)gh * WW + gw;
      float v[8];
      #pragma unroll
      for (int q = 0; q < 8; ++q) v[q] = inb ? xp[(size_t)q * HW] : 0.f;
      uint4 u;
      u.x = pk2(v[0], v[1]); u.y = pk2(v[2], v[3]);
      u.z = pk2(v[4], v[5]); u.w = pk2(v[6], v[7]);
      *(uint4*)(lds + XS_OFF + r * XS_ROW + slot * XS_SLOT + wI * 16) = u;
    }
  }
  __syncthreads();   // A glls (vmcnt) + prologue ds_writes (lgkm) all visible

  const unsigned char* Asb = lds + (unsigned)(half * 1024 + ln * 16);
  const unsigned char* Bsb = lds + XS_OFF + (unsigned)(half * XS_SLOT + ln * 16);

  bf16x8 ob = (bf16x8)(short)0;      // one-hot B frag for bias kstep
  if (half == 0) ob[0] = (short)0x3F80;

  float gv[5][8];    // restage registers (live across one K-loop)

  #pragma unroll 1
  for (int it = 0; it < 4; ++it) {
    const bool rst = (it < 3);

    // ring byte offsets per dh: x row hbase+it*2+row-1+dh -> slot (it*2+row+dh)&3
    unsigned ro[3];
    #pragma unroll
    for (int dh = 0; dh < 3; ++dh)
      ro[dh] = (unsigned)(((it * 2 + row + dh) & 3) * XS_ROW);

    // issue restage loads at tile start: rows hbase+it*2+3, +4 (full width)
    // 2 rows x 8 slots x 130 cols = 2080 granules
    if (rst) {
      #pragma unroll
      for (int i = 0; i < 5; ++i) {
        const int g = tid + i * 512;
        if (g < 2080) {
          const int rr   = g / 1040;
          const int rest = g - rr * 1040;
          const int slot = rest / 130;
          const int wI   = rest - slot * 130;
          const int gh = hbase + it * 2 + 3 + rr;
          const int gw = wI - 1;
          const bool inb = ((unsigned)gh < HH) && ((unsigned)gw < WW);
          const float* xp = x + (size_t)(b * CIN + slot * 8) * HW + (size_t)gh * WW + gw;
          #pragma unroll
          for (int q = 0; q < 8; ++q) gv[i][q] = inb ? xp[(size_t)q * HW] : 0.f;
        }
      }
    }

    // ---- K-loop: 9 taps x 4 q-steps, mf=2 x nf=4 (6 reads per 8 MFMA) ----
    f32x16 acc[2][4];
    #pragma unroll
    for (int mf = 0; mf < 2; ++mf)
      #pragma unroll
      for (int nf = 0; nf < 4; ++nf) acc[mf][nf] = (f32x16)(0.f);

    #pragma unroll
    for (int t = 0; t < 9; ++t) {
      const unsigned aoff = APERM_d[a][t];
      const unsigned bbt = ro[t / 3] + (unsigned)((t % 3) * 16);
      #pragma unroll
      for (int q = 0; q < 4; ++q) {
        const bf16x8 af0 = *(const bf16x8*)(Asb + aoff + q * 2048);
        const bf16x8 af1 = *(const bf16x8*)(Asb + aoff + q * 2048 + 512);
        const unsigned bb = bbt + (unsigned)(q * 2 * XS_SLOT);
        bf16x8 bfv[4];
        #pragma unroll
        for (int nf = 0; nf < 4; ++nf)
          bfv[nf] = *(const bf16x8*)(Bsb + bb + nf * 512);
        #pragma unroll
        for (int nf = 0; nf < 4; ++nf) {
          acc[0][nf] = __builtin_amdgcn_mfma_f32_32x32x16_bf16(af0, bfv[nf], acc[0][nf], 0, 0, 0);
          acc[1][nf] = __builtin_amdgcn_mfma_f32_32x32x16_bf16(af1, bfv[nf], acc[1][nf], 0, 0, 0);
        }
      }
    }
    {  // bias kstep: one-hot B adds bias[cm] to every column
      const bf16x8 af0 = *(const bf16x8*)(Asb + 36 * 2048);
      const bf16x8 af1 = *(const bf16x8*)(Asb + 36 * 2048 + 512);
      #pragma unroll
      for (int nf = 0; nf < 4; ++nf) {
        acc[0][nf] = __builtin_amdgcn_mfma_f32_32x32x16_bf16(af0, ob, acc[0][nf], 0, 0, 0);
        acc[1][nf] = __builtin_amdgcn_mfma_f32_32x32x16_bf16(af1, ob, acc[1][nf], 0, 0, 0);
      }
    }

    // ---- NT stores (fire-and-forget; never gate a barrier) ----
    const int hout = hbase + it * 2 + row;
    #pragma unroll
    for (int mf = 0; mf < 2; ++mf)
      #pragma unroll
      for (int nf = 0; nf < 4; ++nf) {
        const f32x16 v = acc[mf][nf];
        float* op = out + (((size_t)(a * NB + b) * COUT + mf * 32 + 4 * half) * HH
                           + hout) * WW + nf * 32 + ln;
        #pragma unroll
        for (int g = 0; g < 16; ++g)
          __builtin_nontemporal_store(v[g], op + (size_t)((g & 3) + 8 * (g >> 2)) * HW);
      }

    // ---- barrier pair + pack (counted vmcnt via issue-before-stores order) ----
    if (rst) {
      lgkm_barrier();                // all waves' ring reads complete (lgkm only)
      #pragma unroll
      for (int i = 0; i < 5; ++i) {
        const int g = tid + i * 512;
        if (g < 2080) {
          const int rr   = g / 1040;
          const int rest = g - rr * 1040;
          const int slot = rest / 130;
          const int wI   = rest - slot * 130;
          // x row hbase+it*2+3+rr -> ring slot (it*2+4+rr)&3
          uint4 u;
          u.x = pk2(gv[i][0], gv[i][1]); u.y = pk2(gv[i][2], gv[i][3]);
          u.z = pk2(gv[i][4], gv[i][5]); u.w = pk2(gv[i][6], gv[i][7]);
          *(uint4*)(lds + XS_OFF + (unsigned)(((it * 2 + 4 + rr) & 3) * XS_ROW)
                    + slot * XS_SLOT + wI * 16) = u;
        }
      }
      lgkm_barrier();                // new rows visible for it+1
    }
  }
}

extern "C" void kernel_launch(void* const* d_in, const int* in_sizes, int n_in,
                              void* d_out, int out_size, void* d_ws, size_t ws_size,
                              hipStream_t stream) {
  const float* x    = (const float*)d_in[0];
  const float* wgt  = (const float*)d_in[1];
  const float* bias = (const float*)d_in[2];
  float* out = (float*)d_out;
  unsigned short* A = (unsigned short*)d_ws;   // 75,776 B

  build_A_kernel<<<148, 256, 0, stream>>>(wgt, bias, A);
  aconv_v16_kernel<<<256, 512, 0, stream>>>(x, A, out);
}

// Round 17
// 97.442 us; speedup vs baseline: 1.1794x; 1.1794x over previous
//
#include <hip/hip_runtime.h>

// AdaptiveAngleConv round 17: R14 (98.4 us) + per-wave tap-phase rotation.
//   Wave w iterates taps in order (t + w) mod 9 -> read-bursts and MFMA-bursts
//   of the 8 waves desynchronize, raising LDS-pipe duty cycle (the 46 us
//   critical resource, measured ~48% utilized in the lockstep schedule).
//   Accumulation order per wave changes only (bf16-tolerant).
// Everything else identical to R14: ring of 4 full-width x rows, (it, wh)
// wh-inner tiles, x fetched once, loads at odd-tile start -> pack between
// lgkm-only barrier pair, NT stores never gate a barrier, gll A-staging,
// bv bias init, acc 64 AGPR, 512 thr / 8 waves.
// LDS: A 73,728 + ring 4*16,640 = 140,288 B.

#define CIN 64
#define COUT 64
#define HH 128
#define WW 128
#define NB 16
#define HW (HH*WW)

typedef short bf16x8 __attribute__((ext_vector_type(8)));
typedef float f32x16 __attribute__((ext_vector_type(16)));
#define AS1 __attribute__((address_space(1)))
#define AS3 __attribute__((address_space(3)))

// APERM_d[a][t] = PERMS[a][t] * 8192 : A slab byte offset paired with x-tap t
// (v13/R14-validated, absmax 0.5).
__device__ __constant__ unsigned APERM_d[4][9] = {
  {0,8192,16384,24576,32768,40960,49152,57344,65536},
  {24576,0,8192,49152,32768,16384,57344,65536,40960},
  {49152,24576,0,57344,32768,8192,65536,40960,16384},
  {57344,49152,24576,65536,32768,0,40960,16384,8192},
};

static __device__ __forceinline__ unsigned short f2bf(float f) {
  unsigned u = __builtin_bit_cast(unsigned, f);
  return (unsigned short)((u + 0x7FFFu + ((u >> 16) & 1u)) >> 16);
}
static __device__ __forceinline__ unsigned pk2(float lo, float hi) {
  return (unsigned)f2bf(lo) | ((unsigned)f2bf(hi) << 16);
}

// Canonical A (R4..R14-validated): e = ((kc*2 + half)*64 + cm)*8 + j ; kc = s*4+q ;
// ci = q*16 + half*8 + j ; value = W[cm][ci][s]. 36,864 bf16 = 73,728 B.
__global__ void build_A_kernel(const float* __restrict__ wgt,
                               unsigned short* __restrict__ A) {
  const int e = blockIdx.x * 256 + threadIdx.x;
  const int j = e & 7;
  const int cm = (e >> 3) & 63;
  const int half = (e >> 9) & 1;
  const int kc = e >> 10;
  const int s = kc >> 2, q = kc & 3;
  const int ci = q * 16 + half * 8 + j;
  A[e] = f2bf(wgt[(cm * CIN + ci) * 9 + s]);
}

static __device__ __forceinline__ void lgkm_barrier() {
  asm volatile("s_waitcnt lgkmcnt(0)" ::: "memory");
  __builtin_amdgcn_s_barrier();
}

// ring: byte(rs, ci, wI) = XS_OFF + rs*XS_ROW + (ci>>3)*XS_SLOT + wI*16 + (ci&7)*2
//   x row hx -> slot (hx - hbase + 1) & 3 ; wI = 0..129 = x col -1..128
#define XS_SLOT 2080
#define XS_ROW  16640
#define XS_OFF  73728
#define LDS_BYTES (XS_OFF + 4 * XS_ROW)   // 140,288 B

__global__ __launch_bounds__(512) void aconv_v17_kernel(
    const float* __restrict__ x,              // [B][CIN][H][W] fp32
    const unsigned short* __restrict__ Ag,    // canonical W, 36,864 bf16
    const float* __restrict__ bias,           // [COUT]
    float* __restrict__ out)                  // [4][B][COUT][H][W] fp32
{
  __shared__ __align__(16) unsigned char lds[LDS_BYTES];

  const int tid = threadIdx.x;
  const int lane = tid & 63;
  const int wid = tid >> 6;          // 8 waves
  const int a   = wid >> 1;          // angle
  const int row = wid & 1;           // output row within 2-row tile
  const int half = lane >> 5;
  const int ln = lane & 31;

  const int b   = blockIdx.x >> 4;
  const int rem = blockIdx.x & 15;
  const int hbase = rem * 8;

  const unsigned char* Agb = (const unsigned char*)Ag;
  AS3 unsigned char* ldsa = (AS3 unsigned char*)lds;

  // ---- per-wave rotated tap tables (wave-uniform, built once) ----
  // wave wid iterates taps tt = (t + wid) % 9
  unsigned aofr[9]; int dhsel[9]; unsigned dwr[9];
  #pragma unroll
  for (int t = 0; t < 9; ++t) {
    int tt = t + wid; if (tt >= 9) tt -= 9;
    aofr[t]  = APERM_d[a][tt];
    dhsel[t] = tt / 3;
    dwr[t]   = (unsigned)((tt - (tt / 3) * 3) * 16);
  }

  // ---- stage A via global_load_lds: 72 granules of 1024 B (zero staging VGPRs) ----
  #pragma unroll
  for (int j = 0; j < 9; ++j) {
    const int i = wid + j * 8;       // 0..71
    __builtin_amdgcn_global_load_lds(
        (const AS1 unsigned*)(Agb + i * 1024 + lane * 16),
        (AS3 unsigned*)(ldsa + i * 1024), 16, 0, 0);
  }

  // ---- bias fragments ----
  float bv[2][16];
  #pragma unroll
  for (int mf = 0; mf < 2; ++mf)
    #pragma unroll
    for (int g = 0; g < 16; ++g)
      bv[mf][g] = bias[mf * 32 + (g & 3) + 8 * (g >> 2) + 4 * half];

  // ---- prologue: stage x rows hbase-1..hbase+2 (full width) into slots 0..3 ----
  #pragma unroll
  for (int i = 0; i < 9; ++i) {
    const int g = tid + i * 512;
    if (g < 4160) {
      const int r    = g / 1040;
      const int rest = g - r * 1040;
      const int slot = rest / 130;
      const int wI   = rest - slot * 130;
      const int gh = hbase - 1 + r;
      const int gw = wI - 1;
      const bool inb = ((unsigned)gh < HH) && ((unsigned)gw < WW);
      const float* xp = x + (size_t)(b * CIN + slot * 8) * HW + (size_t)gh * WW + gw;
      float v[8];
      #pragma unroll
      for (int q = 0; q < 8; ++q) v[q] = inb ? xp[(size_t)q * HW] : 0.f;
      uint4 u;
      u.x = pk2(v[0], v[1]); u.y = pk2(v[2], v[3]);
      u.z = pk2(v[4], v[5]); u.w = pk2(v[6], v[7]);
      *(uint4*)(lds + XS_OFF + r * XS_ROW + slot * XS_SLOT + wI * 16) = u;
    }
  }
  __syncthreads();   // A glls (vmcnt) + prologue ds_writes (lgkm) all visible

  const unsigned char* Asb = lds + (unsigned)(half * 1024 + ln * 16);
  const unsigned char* Bsb = lds + XS_OFF + (unsigned)(half * XS_SLOT + ln * 16);

  float gv[5][8];    // restage registers (live only across odd tiles)

  #pragma unroll 1
  for (int ti = 0; ti < 8; ++ti) {
    const int it = ti >> 1;          // h pair 0..3
    const int wh = ti & 1;           // w half (inner)
    const bool rst = (wh == 1) && (it < 3);

    // ring byte offsets per dh, then per-wave rotated tap offsets
    unsigned ro0, ro1, ro2;
    ro0 = (unsigned)(((it * 2 + row    ) & 3) * XS_ROW);
    ro1 = (unsigned)(((it * 2 + row + 1) & 3) * XS_ROW);
    ro2 = (unsigned)(((it * 2 + row + 2) & 3) * XS_ROW);
    unsigned bofr[9];
    #pragma unroll
    for (int t = 0; t < 9; ++t) {
      const int ds = dhsel[t];
      const unsigned rsel = (ds == 0) ? ro0 : ((ds == 1) ? ro1 : ro2);
      bofr[t] = rsel + dwr[t];
    }

    // issue restage loads at odd-tile start: rows hbase+it*2+3, +4 (full width)
    if (rst) {
      #pragma unroll
      for (int i = 0; i < 5; ++i) {
        const int g = tid + i * 512;
        if (g < 2080) {
          const int rr   = g / 1040;
          const int rest = g - rr * 1040;
          const int slot = rest / 130;
          const int wI   = rest - slot * 130;
          const int gh = hbase + it * 2 + 3 + rr;
          const int gw = wI - 1;
          const bool inb = ((unsigned)gh < HH) && ((unsigned)gw < WW);
          const float* xp = x + (size_t)(b * CIN + slot * 8) * HW + (size_t)gh * WW + gw;
          #pragma unroll
          for (int q = 0; q < 8; ++q) gv[i][q] = inb ? xp[(size_t)q * HW] : 0.f;
        }
      }
    }

    // ---- acc init with bias; K-loop: 9 rotated taps x 4 q-steps ----
    f32x16 acc[2][2];
    #pragma unroll
    for (int mf = 0; mf < 2; ++mf)
      #pragma unroll
      for (int nf = 0; nf < 2; ++nf)
        #pragma unroll
        for (int g = 0; g < 16; ++g)
          acc[mf][nf][g] = bv[mf][g];

    const unsigned whb = (unsigned)(wh * 64 * 16);
    #pragma unroll
    for (int t = 0; t < 9; ++t) {
      const unsigned aoff = aofr[t];
      const unsigned bbt = bofr[t] + whb;
      #pragma unroll
      for (int q = 0; q < 4; ++q) {
        const bf16x8 af0 = *(const bf16x8*)(Asb + aoff + q * 2048);
        const bf16x8 af1 = *(const bf16x8*)(Asb + aoff + q * 2048 + 512);
        const unsigned bb = bbt + (unsigned)(q * 2 * XS_SLOT);
        const bf16x8 bf0 = *(const bf16x8*)(Bsb + bb);
        const bf16x8 bf1 = *(const bf16x8*)(Bsb + bb + 512);
        acc[0][0] = __builtin_amdgcn_mfma_f32_32x32x16_bf16(af0, bf0, acc[0][0], 0, 0, 0);
        acc[0][1] = __builtin_amdgcn_mfma_f32_32x32x16_bf16(af0, bf1, acc[0][1], 0, 0, 0);
        acc[1][0] = __builtin_amdgcn_mfma_f32_32x32x16_bf16(af1, bf0, acc[1][0], 0, 0, 0);
        acc[1][1] = __builtin_amdgcn_mfma_f32_32x32x16_bf16(af1, bf1, acc[1][1], 0, 0, 0);
      }
    }

    // ---- NT stores (fire-and-forget; never gate a barrier) ----
    const int hout = hbase + it * 2 + row;
    #pragma unroll
    for (int mf = 0; mf < 2; ++mf)
      #pragma unroll
      for (int nf = 0; nf < 2; ++nf) {
        const f32x16 v = acc[mf][nf];
        float* op = out + (((size_t)(a * NB + b) * COUT + mf * 32 + 4 * half) * HH
                           + hout) * WW + wh * 64 + nf * 32 + ln;
        #pragma unroll
        for (int g = 0; g < 16; ++g)
          __builtin_nontemporal_store(v[g], op + (size_t)((g & 3) + 8 * (g >> 2)) * HW);
      }

    // ---- barrier pair + pack only after odd tiles (except the last) ----
    if (rst) {
      lgkm_barrier();                // all waves' ring reads complete (lgkm only)
      #pragma unroll
      for (int i = 0; i < 5; ++i) {
        const int g = tid + i * 512;
        if (g < 2080) {
          const int rr   = g / 1040;
          const int rest = g - rr * 1040;
          const int slot = rest / 130;
          const int wI   = rest - slot * 130;
          uint4 u;
          u.x = pk2(gv[i][0], gv[i][1]); u.y = pk2(gv[i][2], gv[i][3]);
          u.z = pk2(gv[i][4], gv[i][5]); u.w = pk2(gv[i][6], gv[i][7]);
          *(uint4*)(lds + XS_OFF + (unsigned)(((it * 2 + 4 + rr) & 3) * XS_ROW)
                    + slot * XS_SLOT + wI * 16) = u;
        }
      }
      lgkm_barrier();                // new rows visible for it+1
    }
  }
}

extern "C" void kernel_launch(void* const* d_in, const int* in_sizes, int n_in,
                              void* d_out, int out_size, void* d_ws, size_t ws_size,
                              hipStream_t stream) {
  const float* x    = (const float*)d_in[0];
  const float* wgt  = (const float*)d_in[1];
  const float* bias = (const float*)d_in[2];
  float* out = (float*)d_out;
  unsigned short* A = (unsigned short*)d_ws;   // 73,728 B

  build_A_kernel<<<144, 256, 0, stream>>>(wgt, A);
  aconv_v17_kernel<<<256, 512, 0, stream>>>(x, A, bias, out);
}